// Round 1
// baseline (270.917 us; speedup 1.0000x reference)
//
#include <hip/hip_runtime.h>
#include <stdint.h>

// ---------------------------------------------------------------------------
// MAB block: O = LN2(O1 + relu(O1@Wo+bo)), O1 = LN1(Q + MHA(Q,K,V,mask))
// Q=X@Wq+bq, K=Y@Wk+bk, V=Y@Wv+bv ; logits scaled by 1/sqrt(1024)
// All GEMMs in bf16 MFMA (f32 accum). B=8, N=1024, DIM=1024, H=8, Dh=128.
// ---------------------------------------------------------------------------

typedef unsigned short u16;
typedef unsigned int u32;
typedef __attribute__((ext_vector_type(8))) short s16x8;   // bf16x8 frag (4 VGPR)
typedef __attribute__((ext_vector_type(4))) float f32x4;   // MFMA C/D
typedef __attribute__((ext_vector_type(4))) u16 u16x4;

typedef __attribute__((address_space(1))) const void* as1cv;
typedef __attribute__((address_space(3))) void* as3v;

#define DEVINL __device__ __forceinline__

DEVINL u16 f2bf(float f) {
  union { float f; u32 u; } v; v.f = f;
  return (u16)((v.u + 0x7FFFu + ((v.u >> 16) & 1u)) >> 16);  // RNE
}
DEVINL float bf2f(u16 x) {
  union { u32 u; float f; } v; v.u = ((u32)x) << 16;
  return v.f;
}
DEVINL void gload_lds16(const void* g, void* l) {
  __builtin_amdgcn_global_load_lds((as1cv)g, (as3v)l, 16, 0, 0);
}
DEVINL f32x4 mfma16(s16x8 a, s16x8 b, f32x4 c) {
  return __builtin_amdgcn_mfma_f32_16x16x32_bf16(a, b, c, 0, 0, 0);
}

// ---------------------------------------------------------------------------
// mask prep: detect layout (bool bytes / int32 / float32) and expand to
// f32 bias (-1e30 for masked). Only first 2048 words scanned (in-bounds for
// every candidate layout of 8192 elements).
// ---------------------------------------------------------------------------
__global__ void prep_mask(const u32* __restrict__ mraw, float* __restrict__ maskb) {
  __shared__ int mode;
  int t = threadIdx.x;
  int fB = 0, fF = 0;
  for (int i = t; i < 2048; i += 256) {
    u32 v = mraw[i];
    if (v == 0x3F800000u) fF = 1;
    else if (v > 1u) fB = 1;
  }
  if (t == 0) mode = 0;
  __syncthreads();
  if (fB) atomicOr(&mode, 1);
  if (fF) atomicOr(&mode, 2);
  __syncthreads();
  int md = mode;
  int idx = blockIdx.x * 256 + t;  // grid = 32 blocks -> 8192
  int v;
  if (md & 1)       v = ((const unsigned char*)mraw)[idx] != 0;  // bool bytes
  else if (md & 2)  v = ((const float*)mraw)[idx] != 0.0f;       // float32
  else              v = ((const int*)mraw)[idx] != 0;            // int32
  maskb[idx] = v ? -1e30f : 0.0f;
}

// ---------------------------------------------------------------------------
// f32 -> bf16 bulk convert (vectorized, grid-stride)
// ---------------------------------------------------------------------------
__global__ void cvt_f2bf(const float* __restrict__ in, u16* __restrict__ out, int n4) {
  int i = blockIdx.x * blockDim.x + threadIdx.x;
  int stride = gridDim.x * blockDim.x;
  for (; i < n4; i += stride) {
    float4 v = *(const float4*)(in + (size_t)i * 4);
    u16x4 o; o[0] = f2bf(v.x); o[1] = f2bf(v.y); o[2] = f2bf(v.z); o[3] = f2bf(v.w);
    *(u16x4*)(out + (size_t)i * 4) = o;
  }
}

// ---------------------------------------------------------------------------
// weight transpose + convert: W[k][n] f32 -> Wt[n][k] bf16 (1024x1024)
// grid (32,32,4), block (32,8)
// ---------------------------------------------------------------------------
__global__ void transpose_cvt(const float* __restrict__ W0, const float* __restrict__ W1,
                              const float* __restrict__ W2, const float* __restrict__ W3,
                              u16* __restrict__ T0, u16* __restrict__ T1,
                              u16* __restrict__ T2, u16* __restrict__ T3) {
  const float* W = (blockIdx.z == 0) ? W0 : (blockIdx.z == 1) ? W1 : (blockIdx.z == 2) ? W2 : W3;
  u16* T = (blockIdx.z == 0) ? T0 : (blockIdx.z == 1) ? T1 : (blockIdx.z == 2) ? T2 : T3;
  __shared__ float tile[32][33];
  int tx = threadIdx.x, ty = threadIdx.y;
  int N0 = blockIdx.x << 5, K0 = blockIdx.y << 5;
#pragma unroll
  for (int i = 0; i < 4; ++i)
    tile[ty + i * 8][tx] = W[(size_t)(K0 + ty + i * 8) * 1024 + N0 + tx];
  __syncthreads();
#pragma unroll
  for (int i = 0; i < 4; ++i)
    T[(size_t)(N0 + ty + i * 8) * 1024 + K0 + tx] = f2bf(tile[tx][ty + i * 8]);
}

// ---------------------------------------------------------------------------
// NT GEMM: C[m][n] = sum_k A[m][k]*Bt[n][k] + bias[n]    (M=8192, N=K=1024)
// 128x128 tile, BK=64, 4 waves (2x2), mfma 16x16x32 bf16.
// LDS XOR-swizzled (byte ^= (row&7)<<4), source pre-swizzled for
// global_load_lds (linear dest).
// MODE 0: write outF (f32) + outBF (bf16)  [Q]
// MODE 1: write outBF                       [K, or Q lean]
// MODE 2: write outBF transposed Vt[(b*1024+n)][m%1024]  [V]
// MODE 3: r = resid + relu(acc+bias); write outF          [O-proj]
// ---------------------------------------------------------------------------
template <int MODE>
__global__ __launch_bounds__(256, 2) void gemm_nt(
    const u16* __restrict__ A, const u16* __restrict__ Bt,
    const float* __restrict__ bias, float* __restrict__ outF,
    u16* __restrict__ outBF, const float* __restrict__ resid) {
  __shared__ u16 lA[128 * 64];
  __shared__ u16 lB[128 * 64];

  const int id = blockIdx.x;               // 512 blocks (64 m x 8 n)
  const int cpx = gridDim.x >> 3;
  const int swz = (id & 7) * cpx + (id >> 3);  // XCD-contiguous (512%8==0)
  const int mb = swz >> 3;                  // 0..63
  const int nb = swz & 7;                   // 0..7

  const int tid = threadIdx.x;
  const int w = tid >> 6, l = tid & 63;
  const int wm = w >> 1, wn = w & 1;
  const int lrow = l & 15, lk = l >> 4;

  // staging constants: each call = 1024B = 8 rows x 128B
  const int sr = l >> 3;                           // row within call
  const int scol = ((l & 7) << 4) ^ (sr << 4);     // pre-swizzled src col byte
  const char* gA = (const char*)A + (size_t)(mb * 128) * 2048;
  const char* gB = (const char*)Bt + (size_t)(nb * 128) * 2048;

  f32x4 acc[4][4];
#pragma unroll
  for (int i = 0; i < 4; ++i)
#pragma unroll
    for (int j = 0; j < 4; ++j) acc[i][j] = f32x4{0.f, 0.f, 0.f, 0.f};

  for (int kt = 0; kt < 16; ++kt) {
    const int kb = kt * 128;  // byte offset within a row
#pragma unroll
    for (int c = 0; c < 4; ++c) {
      int row = (w * 4 + c) * 8 + sr;
      gload_lds16(gA + (size_t)row * 2048 + kb + scol, (char*)lA + (w * 4 + c) * 1024);
      gload_lds16(gB + (size_t)row * 2048 + kb + scol, (char*)lB + (w * 4 + c) * 1024);
    }
    __syncthreads();
#pragma unroll
    for (int kc = 0; kc < 2; ++kc) {
      s16x8 af[4], bfr[4];
#pragma unroll
      for (int mi = 0; mi < 4; ++mi) {
        int row = wm * 64 + mi * 16 + lrow;
        int off = row * 128 + ((lk * 16 + kc * 64) ^ ((row & 7) << 4));
        af[mi] = *(const s16x8*)((const char*)lA + off);
      }
#pragma unroll
      for (int ni = 0; ni < 4; ++ni) {
        int row = wn * 64 + ni * 16 + lrow;
        int off = row * 128 + ((lk * 16 + kc * 64) ^ ((row & 7) << 4));
        bfr[ni] = *(const s16x8*)((const char*)lB + off);
      }
#pragma unroll
      for (int mi = 0; mi < 4; ++mi)
#pragma unroll
        for (int ni = 0; ni < 4; ++ni)
          acc[mi][ni] = mfma16(af[mi], bfr[ni], acc[mi][ni]);
    }
    __syncthreads();
  }

  // epilogue: C/D layout col=lane&15, row=(lane>>4)*4+reg
  const int growb = mb * 128 + wm * 64;
  const int gcolb = nb * 128 + wn * 64;
  float bs[4];
#pragma unroll
  for (int ni = 0; ni < 4; ++ni) bs[ni] = bias[gcolb + ni * 16 + lrow];

#pragma unroll
  for (int mi = 0; mi < 4; ++mi) {
    const int grow0 = growb + mi * 16 + lk * 4;
#pragma unroll
    for (int ni = 0; ni < 4; ++ni) {
      const int gcol = gcolb + ni * 16 + lrow;
      if (MODE == 2) {
        u16x4 pk;
#pragma unroll
        for (int r = 0; r < 4; ++r) pk[r] = f2bf(acc[mi][ni][r] + bs[ni]);
        size_t flat = ((size_t)((grow0 >> 10) << 10) + gcol) * 1024 + (grow0 & 1023);
        *(u16x4*)(outBF + flat) = pk;
      } else {
#pragma unroll
        for (int r = 0; r < 4; ++r) {
          float v = acc[mi][ni][r] + bs[ni];
          size_t idx = (size_t)(grow0 + r) * 1024 + gcol;
          if (MODE == 0) { outF[idx] = v; outBF[idx] = f2bf(v); }
          if (MODE == 1) { outBF[idx] = f2bf(v); }
          if (MODE == 3) { outF[idx] = resid[idx] + fmaxf(v, 0.f); }
        }
      }
    }
  }
}

// ---------------------------------------------------------------------------
// flash attention: grid (NX/64, B*H), 4 waves x 16 q-rows, KV tile = 64.
// Qbf: [8192][1024] bf16 (head slice cols h*128..). Kbf same layout.
// Vt:  [(b*1024 + h*128 + d)][key] bf16 (pre-transposed by V-GEMM).
// maskb: [B][1024] f32 bias (0 or -1e30).  out: attn f32 [8192][1024].
// ---------------------------------------------------------------------------
__global__ __launch_bounds__(256, 2) void attn_fwd(
    const u16* __restrict__ Qbf, const u16* __restrict__ Kbf,
    const u16* __restrict__ Vt, const float* __restrict__ maskb,
    float* __restrict__ attnO) {
  __shared__ u16 lK[64 * 128];     // [key][d] swizzled rows of 256B
  __shared__ u16 lV[128 * 64];     // [d][key] swizzled rows of 128B
  __shared__ u16 lP[4][16 * 80];   // per-wave P re-layout [q][key], pad to 80

  const int qb = blockIdx.x;   // 0..15
  const int bh = blockIdx.y;   // 0..63
  const int b = bh >> 3, h = bh & 7;
  const int tid = threadIdx.x;
  const int w = tid >> 6, l = tid & 63;
  const int lrow = l & 15, lk = l >> 4;

  // Q fragments (A operand: lane row = l&15, 8 consecutive d per lane)
  const u16* Qrow = Qbf + ((size_t)(b * 1024 + qb * 64 + w * 16 + lrow)) * 1024 + h * 128;
  s16x8 qf[4];
#pragma unroll
  for (int kc = 0; kc < 4; ++kc) qf[kc] = *(const s16x8*)(Qrow + lk * 8 + kc * 32);

  const char* gK = (const char*)(Kbf + ((size_t)(b * 1024)) * 1024 + h * 128);
  const char* gV = (const char*)(Vt + ((size_t)(b * 1024 + h * 128)) * 1024);
  const float* mrow = maskb + b * 1024;

  float m_[4], l_[4];
  f32x4 oacc[8];
#pragma unroll
  for (int r = 0; r < 4; ++r) { m_[r] = -1e30f; l_[r] = 0.f; }
#pragma unroll
  for (int i = 0; i < 8; ++i) oacc[i] = f32x4{0.f, 0.f, 0.f, 0.f};

  for (int t = 0; t < 16; ++t) {
    const int kbase = t * 64;
    // stage K tile (64 rows x 256B), 4 calls/wave of 4 rows each
    {
      const int srk = l >> 4;
      const int sck = (l & 15) << 4;
#pragma unroll
      for (int c = 0; c < 4; ++c) {
        int row = (w * 4 + c) * 4 + srk;
        int scolk = sck ^ ((row & 7) << 4);
        gload_lds16(gK + (size_t)(kbase + row) * 2048 + scolk, (char*)lK + (w * 4 + c) * 1024);
      }
      // stage V tile (128 d-rows x 128B), 4 calls/wave of 8 rows each
      const int srv = l >> 3;
      const int scv = ((l & 7) << 4) ^ ((srv & 7) << 4);
#pragma unroll
      for (int c = 0; c < 4; ++c) {
        int d = (w * 4 + c) * 8 + srv;
        gload_lds16(gV + (size_t)d * 2048 + kbase * 2 + scv, (char*)lV + (w * 4 + c) * 1024);
      }
    }
    __syncthreads();

    // S = Q K^T  (m=q row, n=key)
    f32x4 sc[4];
#pragma unroll
    for (int nc = 0; nc < 4; ++nc) sc[nc] = f32x4{0.f, 0.f, 0.f, 0.f};
#pragma unroll
    for (int kc = 0; kc < 4; ++kc) {
#pragma unroll
      for (int nc = 0; nc < 4; ++nc) {
        int row = nc * 16 + lrow;
        int off = row * 256 + ((lk * 16 + kc * 64) ^ ((row & 7) << 4));
        s16x8 kf = *(const s16x8*)((const char*)lK + off);
        sc[nc] = mfma16(qf[kc], kf, sc[nc]);
      }
    }

    // online softmax (rows = lk*4+r, cols = nc*16+lrow)
    float s[4][4];
#pragma unroll
    for (int nc = 0; nc < 4; ++nc) {
      float mb_ = mrow[kbase + nc * 16 + lrow];
#pragma unroll
      for (int r = 0; r < 4; ++r) s[nc][r] = sc[nc][r] * 0.03125f + mb_;
    }
    float rm[4];
#pragma unroll
    for (int r = 0; r < 4; ++r)
      rm[r] = fmaxf(fmaxf(s[0][r], s[1][r]), fmaxf(s[2][r], s[3][r]));
#pragma unroll
    for (int msk = 1; msk <= 8; msk <<= 1)
#pragma unroll
      for (int r = 0; r < 4; ++r) rm[r] = fmaxf(rm[r], __shfl_xor(rm[r], msk));

    float nm[4], so[4];
#pragma unroll
    for (int r = 0; r < 4; ++r) {
      nm[r] = fmaxf(m_[r], rm[r]);
      so[r] = exp2f((m_[r] - nm[r]) * 1.44269504f);
      m_[r] = nm[r];
    }
    float p[4][4];
#pragma unroll
    for (int nc = 0; nc < 4; ++nc)
#pragma unroll
      for (int r = 0; r < 4; ++r)
        p[nc][r] = exp2f((s[nc][r] - nm[r]) * 1.44269504f);
    float rs[4];
#pragma unroll
    for (int r = 0; r < 4; ++r) rs[r] = (p[0][r] + p[1][r]) + (p[2][r] + p[3][r]);
#pragma unroll
    for (int msk = 1; msk <= 8; msk <<= 1)
#pragma unroll
      for (int r = 0; r < 4; ++r) rs[r] += __shfl_xor(rs[r], msk);
#pragma unroll
    for (int r = 0; r < 4; ++r) l_[r] = l_[r] * so[r] + rs[r];
    f32x4 sov = {so[0], so[1], so[2], so[3]};
#pragma unroll
    for (int i = 0; i < 8; ++i) oacc[i] *= sov;

    // P: C-layout -> A-layout via per-wave LDS
#pragma unroll
    for (int nc = 0; nc < 4; ++nc)
#pragma unroll
      for (int r = 0; r < 4; ++r)
        lP[w][(lk * 4 + r) * 80 + nc * 16 + lrow] = f2bf(p[nc][r]);

    // O += P V  (n = d, contraction = key)
#pragma unroll
    for (int kv = 0; kv < 2; ++kv) {
      s16x8 pa = *(const s16x8*)&lP[w][lrow * 80 + kv * 32 + lk * 8];
#pragma unroll
      for (int nd = 0; nd < 8; ++nd) {
        int d = nd * 16 + lrow;
        int off = d * 128 + ((lk * 16 + kv * 64) ^ ((d & 7) << 4));
        s16x8 vb = *(const s16x8*)((const char*)lV + off);
        oacc[nd] = mfma16(pa, vb, oacc[nd]);
      }
    }
    __syncthreads();
  }

  float inv[4];
#pragma unroll
  for (int r = 0; r < 4; ++r)
    inv[r] = (m_[r] > -1e29f) ? (1.0f / l_[r]) : 0.f;  // fully-masked row -> 0

  float* orow = attnO + ((size_t)(b * 1024 + qb * 64 + w * 16 + lk * 4)) * 1024 + h * 128;
#pragma unroll
  for (int nd = 0; nd < 8; ++nd)
#pragma unroll
    for (int r = 0; r < 4; ++r)
      orow[(size_t)r * 1024 + nd * 16 + lrow] = oacc[nd][r] * inv[r];
}

// ---------------------------------------------------------------------------
// fused residual + LayerNorm over 1024 cols. one block per row.
// h = (aF ? aF : bf2f(aBF)) + (badd ? badd : 0); out = LN(h)*g + b
// ---------------------------------------------------------------------------
__global__ __launch_bounds__(256) void ln_fused(
    const float* __restrict__ aF, const u16* __restrict__ aBF,
    const float* __restrict__ badd, const float* __restrict__ g,
    const float* __restrict__ bt, float* __restrict__ outF,
    u16* __restrict__ outBF) {
  const int row = blockIdx.x;
  const int c = threadIdx.x << 2;
  const size_t base = (size_t)row * 1024 + c;
  float4 h;
  if (aF) {
    h = *(const float4*)(aF + base);
  } else {
    u16x4 u = *(const u16x4*)(aBF + base);
    h.x = bf2f(u[0]); h.y = bf2f(u[1]); h.z = bf2f(u[2]); h.w = bf2f(u[3]);
  }
  if (badd) {
    float4 t = *(const float4*)(badd + base);
    h.x += t.x; h.y += t.y; h.z += t.z; h.w += t.w;
  }
  float s = (h.x + h.y) + (h.z + h.w);
  float q = (h.x * h.x + h.y * h.y) + (h.z * h.z + h.w * h.w);
#pragma unroll
  for (int msk = 1; msk < 64; msk <<= 1) {
    s += __shfl_xor(s, msk);
    q += __shfl_xor(q, msk);
  }
  __shared__ float sh[8];
  const int w = threadIdx.x >> 6;
  if ((threadIdx.x & 63) == 0) { sh[w] = s; sh[4 + w] = q; }
  __syncthreads();
  s = (sh[0] + sh[1]) + (sh[2] + sh[3]);
  q = (sh[4] + sh[5]) + (sh[6] + sh[7]);
  const float mu = s * (1.f / 1024.f);
  const float var = q * (1.f / 1024.f) - mu * mu;
  const float rstd = rsqrtf(var + 1e-5f);
  const float4 gv = *(const float4*)(g + c);
  const float4 bv = *(const float4*)(bt + c);
  float4 o;
  o.x = (h.x - mu) * rstd * gv.x + bv.x;
  o.y = (h.y - mu) * rstd * gv.y + bv.y;
  o.z = (h.z - mu) * rstd * gv.z + bv.z;
  o.w = (h.w - mu) * rstd * gv.w + bv.w;
  if (outF) *(float4*)(outF + base) = o;
  if (outBF) {
    u16x4 ub; ub[0] = f2bf(o.x); ub[1] = f2bf(o.y); ub[2] = f2bf(o.z); ub[3] = f2bf(o.w);
    *(u16x4*)(outBF + base) = ub;
  }
}

// ---------------------------------------------------------------------------
extern "C" void kernel_launch(void* const* d_in, const int* in_sizes, int n_in,
                              void* d_out, int out_size, void* d_ws, size_t ws_size,
                              hipStream_t stream) {
  const float* X  = (const float*)d_in[0];
  const float* Y  = (const float*)d_in[1];
  const void*  mask = d_in[2];
  const float* Wq = (const float*)d_in[3];
  const float* bq = (const float*)d_in[4];
  const float* Wk = (const float*)d_in[5];
  const float* bk = (const float*)d_in[6];
  const float* Wv = (const float*)d_in[7];
  const float* bv = (const float*)d_in[8];
  const float* Wo = (const float*)d_in[9];
  const float* bo = (const float*)d_in[10];
  const float* g1 = (const float*)d_in[11];
  const float* b1 = (const float*)d_in[12];
  const float* g2 = (const float*)d_in[13];
  const float* b2 = (const float*)d_in[14];
  float* out = (float*)d_out;

  char* ws = (char*)d_ws;
  const size_t MB = 1024ull * 1024ull;
  // workspace layout (full: ~152MB, lean: ~120MB)
  u16* Xbf = (u16*)(ws + 0);          // 16MB, dead after Q-gemm -> reused as O1bf
  u16* Ybf = (u16*)(ws + 16 * MB);    // 16MB
  u16* Qbf = (u16*)(ws + 32 * MB);    // 16MB
  u16* Kbf = (u16*)(ws + 48 * MB);    // 16MB \ dead after attn
  u16* Vt  = (u16*)(ws + 64 * MB);    // 16MB /  -> reused as O1f (32MB)
  float* attn = (float*)(ws + 80 * MB);  // 32MB, dead after LN1 -> reused as R
  const bool full = ws_size >= 153 * MB;
  float* Qf = full ? (float*)(ws + 112 * MB) : nullptr;  // 32MB (full only)
  const size_t woff = full ? 144 * MB : 112 * MB;
  u16* Wqt = (u16*)(ws + woff + 0 * MB);
  u16* Wkt = (u16*)(ws + woff + 2 * MB);
  u16* Wvt = (u16*)(ws + woff + 4 * MB);
  u16* Wot = (u16*)(ws + woff + 6 * MB);
  float* maskb = (float*)(ws + woff + 8 * MB);  // 32KB
  float* O1f = (float*)(ws + 48 * MB);
  u16* O1bf = Xbf;
  float* R = attn;

  prep_mask<<<dim3(32), dim3(256), 0, stream>>>((const u32*)mask, maskb);
  cvt_f2bf<<<dim3(2048), dim3(256), 0, stream>>>(X, Xbf, 2097152);
  cvt_f2bf<<<dim3(2048), dim3(256), 0, stream>>>(Y, Ybf, 2097152);
  transpose_cvt<<<dim3(32, 32, 4), dim3(32, 8), 0, stream>>>(Wq, Wk, Wv, Wo, Wqt, Wkt, Wvt, Wot);

  if (full)
    gemm_nt<0><<<dim3(512), dim3(256), 0, stream>>>(Xbf, Wqt, bq, Qf, Qbf, nullptr);
  else
    gemm_nt<1><<<dim3(512), dim3(256), 0, stream>>>(Xbf, Wqt, bq, nullptr, Qbf, nullptr);
  gemm_nt<1><<<dim3(512), dim3(256), 0, stream>>>(Ybf, Wkt, bk, nullptr, Kbf, nullptr);
  gemm_nt<2><<<dim3(512), dim3(256), 0, stream>>>(Ybf, Wvt, bv, nullptr, Vt, nullptr);

  attn_fwd<<<dim3(16, 64), dim3(256), 0, stream>>>(Qbf, Kbf, Vt, maskb, attn);

  ln_fused<<<dim3(8192), dim3(256), 0, stream>>>(Qf, full ? nullptr : Qbf, attn,
                                                 g1, b1, O1f, O1bf);
  gemm_nt<3><<<dim3(512), dim3(256), 0, stream>>>(O1bf, Wot, bo, R, nullptr, O1f);
  ln_fused<<<dim3(8192), dim3(256), 0, stream>>>(R, nullptr, nullptr, g2, b2, out, nullptr);
}

// Round 2
// 214.377 us; speedup vs baseline: 1.2637x; 1.2637x over previous
//
#include <hip/hip_runtime.h>
#include <stdint.h>

// ---------------------------------------------------------------------------
// MAB block: O = LN2(O1 + relu(O1@Wo+bo)), O1 = LN1(Q + MHA(Q,K,V,mask))
// ---------------------------------------------------------------------------

typedef unsigned short u16;
typedef unsigned int u32;
typedef __attribute__((ext_vector_type(8))) short s16x8;   // bf16x8 frag (4 VGPR)
typedef __attribute__((ext_vector_type(4))) float f32x4;
typedef __attribute__((ext_vector_type(16))) float f32x16; // 32x32 MFMA C/D
typedef __attribute__((ext_vector_type(4))) u16 u16x4;

typedef __attribute__((address_space(1))) const void* as1cv;
typedef __attribute__((address_space(3))) void* as3v;

#define DEVINL __device__ __forceinline__

DEVINL u16 f2bf(float f) {
  union { float f; u32 u; } v; v.f = f;
  return (u16)((v.u + 0x7FFFu + ((v.u >> 16) & 1u)) >> 16);  // RNE
}
DEVINL float bf2f(u16 x) {
  union { u32 u; float f; } v; v.u = ((u32)x) << 16;
  return v.f;
}
DEVINL void gload_lds16(const void* g, void* l) {
  __builtin_amdgcn_global_load_lds((as1cv)g, (as3v)l, 16, 0, 0);
}
DEVINL f32x4 mfma16(s16x8 a, s16x8 b, f32x4 c) {
  return __builtin_amdgcn_mfma_f32_16x16x32_bf16(a, b, c, 0, 0, 0);
}
DEVINL f32x16 mfma32(s16x8 a, s16x8 b, f32x16 c) {
  return __builtin_amdgcn_mfma_f32_32x32x16_bf16(a, b, c, 0, 0, 0);
}

// ---------------------------------------------------------------------------
// mask prep (detect bool/int/float layout), expand to f32 bias
// ---------------------------------------------------------------------------
__global__ void prep_mask(const u32* __restrict__ mraw, float* __restrict__ maskb) {
  __shared__ int mode;
  int t = threadIdx.x;
  int fB = 0, fF = 0;
  for (int i = t; i < 2048; i += 256) {
    u32 v = mraw[i];
    if (v == 0x3F800000u) fF = 1;
    else if (v > 1u) fB = 1;
  }
  if (t == 0) mode = 0;
  __syncthreads();
  if (fB) atomicOr(&mode, 1);
  if (fF) atomicOr(&mode, 2);
  __syncthreads();
  int md = mode;
  int idx = blockIdx.x * 256 + t;
  int v;
  if (md & 1)       v = ((const unsigned char*)mraw)[idx] != 0;
  else if (md & 2)  v = ((const float*)mraw)[idx] != 0.0f;
  else              v = ((const int*)mraw)[idx] != 0;
  maskb[idx] = v ? -1e30f : 0.0f;
}

__global__ void cvt_f2bf(const float* __restrict__ in, u16* __restrict__ out, int n4) {
  int i = blockIdx.x * blockDim.x + threadIdx.x;
  int stride = gridDim.x * blockDim.x;
  for (; i < n4; i += stride) {
    float4 v = *(const float4*)(in + (size_t)i * 4);
    u16x4 o; o[0] = f2bf(v.x); o[1] = f2bf(v.y); o[2] = f2bf(v.z); o[3] = f2bf(v.w);
    *(u16x4*)(out + (size_t)i * 4) = o;
  }
}

__global__ void transpose_cvt(const float* __restrict__ W0, const float* __restrict__ W1,
                              const float* __restrict__ W2, const float* __restrict__ W3,
                              u16* __restrict__ T0, u16* __restrict__ T1,
                              u16* __restrict__ T2, u16* __restrict__ T3) {
  const float* W = (blockIdx.z == 0) ? W0 : (blockIdx.z == 1) ? W1 : (blockIdx.z == 2) ? W2 : W3;
  u16* T = (blockIdx.z == 0) ? T0 : (blockIdx.z == 1) ? T1 : (blockIdx.z == 2) ? T2 : T3;
  __shared__ float tile[32][33];
  int tx = threadIdx.x, ty = threadIdx.y;
  int N0 = blockIdx.x << 5, K0 = blockIdx.y << 5;
#pragma unroll
  for (int i = 0; i < 4; ++i)
    tile[ty + i * 8][tx] = W[(size_t)(K0 + ty + i * 8) * 1024 + N0 + tx];
  __syncthreads();
#pragma unroll
  for (int i = 0; i < 4; ++i)
    T[(size_t)(N0 + ty + i * 8) * 1024 + K0 + tx] = f2bf(tile[tx][ty + i * 8]);
}

// ---------------------------------------------------------------------------
// NT GEMM (unchanged from round 1): 128x128 tile, BK=64, 4 waves.
// MODE 1: write outBF ; MODE 2: write outBF transposed ; MODE 3: resid+relu f32
// ---------------------------------------------------------------------------
template <int MODE>
__global__ __launch_bounds__(256, 2) void gemm_nt(
    const u16* __restrict__ A, const u16* __restrict__ Bt,
    const float* __restrict__ bias, float* __restrict__ outF,
    u16* __restrict__ outBF, const float* __restrict__ resid) {
  __shared__ u16 lA[128 * 64];
  __shared__ u16 lB[128 * 64];

  const int id = blockIdx.x;
  const int cpx = gridDim.x >> 3;
  const int swz = (id & 7) * cpx + (id >> 3);
  const int mb = swz >> 3;
  const int nb = swz & 7;

  const int tid = threadIdx.x;
  const int w = tid >> 6, l = tid & 63;
  const int wm = w >> 1, wn = w & 1;
  const int lrow = l & 15, lk = l >> 4;

  const int sr = l >> 3;
  const int scol = ((l & 7) << 4) ^ (sr << 4);
  const char* gA = (const char*)A + (size_t)(mb * 128) * 2048;
  const char* gB = (const char*)Bt + (size_t)(nb * 128) * 2048;

  f32x4 acc[4][4];
#pragma unroll
  for (int i = 0; i < 4; ++i)
#pragma unroll
    for (int j = 0; j < 4; ++j) acc[i][j] = f32x4{0.f, 0.f, 0.f, 0.f};

  for (int kt = 0; kt < 16; ++kt) {
    const int kb = kt * 128;
#pragma unroll
    for (int c = 0; c < 4; ++c) {
      int row = (w * 4 + c) * 8 + sr;
      gload_lds16(gA + (size_t)row * 2048 + kb + scol, (char*)lA + (w * 4 + c) * 1024);
      gload_lds16(gB + (size_t)row * 2048 + kb + scol, (char*)lB + (w * 4 + c) * 1024);
    }
    __syncthreads();
#pragma unroll
    for (int kc = 0; kc < 2; ++kc) {
      s16x8 af[4], bfr[4];
#pragma unroll
      for (int mi = 0; mi < 4; ++mi) {
        int row = wm * 64 + mi * 16 + lrow;
        int off = row * 128 + ((lk * 16 + kc * 64) ^ ((row & 7) << 4));
        af[mi] = *(const s16x8*)((const char*)lA + off);
      }
#pragma unroll
      for (int ni = 0; ni < 4; ++ni) {
        int row = wn * 64 + ni * 16 + lrow;
        int off = row * 128 + ((lk * 16 + kc * 64) ^ ((row & 7) << 4));
        bfr[ni] = *(const s16x8*)((const char*)lB + off);
      }
#pragma unroll
      for (int mi = 0; mi < 4; ++mi)
#pragma unroll
        for (int ni = 0; ni < 4; ++ni)
          acc[mi][ni] = mfma16(af[mi], bfr[ni], acc[mi][ni]);
    }
    __syncthreads();
  }

  const int growb = mb * 128 + wm * 64;
  const int gcolb = nb * 128 + wn * 64;
  float bs[4];
#pragma unroll
  for (int ni = 0; ni < 4; ++ni) bs[ni] = bias[gcolb + ni * 16 + lrow];

#pragma unroll
  for (int mi = 0; mi < 4; ++mi) {
    const int grow0 = growb + mi * 16 + lk * 4;
#pragma unroll
    for (int ni = 0; ni < 4; ++ni) {
      const int gcol = gcolb + ni * 16 + lrow;
      if (MODE == 2) {
        u16x4 pk;
#pragma unroll
        for (int r = 0; r < 4; ++r) pk[r] = f2bf(acc[mi][ni][r] + bs[ni]);
        size_t flat = ((size_t)((grow0 >> 10) << 10) + gcol) * 1024 + (grow0 & 1023);
        *(u16x4*)(outBF + flat) = pk;
      } else {
#pragma unroll
        for (int r = 0; r < 4; ++r) {
          float v = acc[mi][ni][r] + bs[ni];
          size_t idx = (size_t)(grow0 + r) * 1024 + gcol;
          if (MODE == 1) { outBF[idx] = f2bf(v); }
          if (MODE == 3) { outF[idx] = resid[idx] + fmaxf(v, 0.f); }
        }
      }
    }
  }
}

// ---------------------------------------------------------------------------
// flash attention v2: swapped QK^T on 32x32x16 MFMA, lane-local softmax rows,
// defer-max rescale, KVBLK=128, QBLK=128 (4 waves x 32 q-rows).
// grid: 512 blocks, 1D. XCD mapping: all 8 q-blocks of one (b,h) on one XCD.
// lK[key][d] / lV[d][key]: 128 rows x 256B, byte ^= (row&15)<<4 swizzle.
// ---------------------------------------------------------------------------
__global__ __launch_bounds__(256, 2) void attn_fwd(
    const u16* __restrict__ Qbf, const u16* __restrict__ Kbf,
    const u16* __restrict__ Vt, const float* __restrict__ maskb,
    float* __restrict__ attnO) {
  __shared__ u16 lK[128 * 128];
  __shared__ u16 lV[128 * 128];

  const int id = blockIdx.x;
  const int xcd = id & 7, seq = id >> 3;
  const int bh = xcd * 8 + (seq >> 3);   // all qb of a bh stay on one XCD
  const int qb = seq & 7;
  const int b = bh >> 3, h = bh & 7;
  const int tid = threadIdx.x;
  const int w = tid >> 6, l = tid & 63;
  const int q32 = l & 31, hi = l >> 5;

  // Q fragments in registers: b-operand, lane&31 = q-row, k=(l>>5)*8+j
  const u16* Qrow = Qbf + ((size_t)(b * 1024 + qb * 128 + w * 32 + q32)) * 1024 + h * 128;
  s16x8 qf[8];
#pragma unroll
  for (int dc = 0; dc < 8; ++dc) qf[dc] = *(const s16x8*)(Qrow + dc * 16 + hi * 8);

  const char* gK = (const char*)(Kbf + ((size_t)(b * 1024)) * 1024 + h * 128);
  const char* gV = (const char*)(Vt + ((size_t)(b * 1024 + h * 128)) * 1024);
  const float* mrow = maskb + b * 1024;

  float m_ = -1e30f, l_ = 0.f;
  f32x16 oacc[4];
#pragma unroll
  for (int i = 0; i < 4; ++i)
#pragma unroll
    for (int r = 0; r < 16; ++r) oacc[i][r] = 0.f;

  const int sr = l >> 4, slot = l & 15;
  const float L2E = 1.44269504f;

  for (int t = 0; t < 8; ++t) {
    const int kbase = t * 128;
    // stage K (128 key-rows x 256B) + V (128 d-rows x 256B), 8+8 calls/wave
#pragma unroll
    for (int c = 0; c < 8; ++c) {
      int row = (w * 8 + c) * 4 + sr;
      int scol = (slot << 4) ^ ((row & 15) << 4);
      gload_lds16(gK + (size_t)(kbase + row) * 2048 + scol, (char*)lK + (w * 8 + c) * 1024);
      gload_lds16(gV + (size_t)row * 2048 + kbase * 2 + scol, (char*)lV + (w * 8 + c) * 1024);
    }
    __syncthreads();

    // S^T = K Q^T : sc[kb] lane holds col q=l&31, rows key = (r&3)+8*(r>>2)+4*hi
    f32x16 sc[4];
#pragma unroll
    for (int kb = 0; kb < 4; ++kb)
#pragma unroll
      for (int r = 0; r < 16; ++r) sc[kb][r] = 0.f;
#pragma unroll
    for (int dc = 0; dc < 8; ++dc) {
#pragma unroll
      for (int kb = 0; kb < 4; ++kb) {
        int row = kb * 32 + q32;
        int off = row * 256 + ((dc * 32 + hi * 16) ^ ((row & 15) << 4));
        s16x8 kf = *(const s16x8*)((const char*)lK + off);
        sc[kb] = mfma32(kf, qf[dc], sc[kb]);
      }
    }

    // scale + mask bias (key = kbase + kb*32 + (r&3)+8*(r>>2)+4*hi)
#pragma unroll
    for (int kb = 0; kb < 4; ++kb) {
      f32x4 mb4[4];
#pragma unroll
      for (int g = 0; g < 4; ++g)
        mb4[g] = *(const f32x4*)(mrow + kbase + kb * 32 + g * 8 + hi * 4);
#pragma unroll
      for (int r = 0; r < 16; ++r)
        sc[kb][r] = sc[kb][r] * 0.03125f + mb4[r >> 2][r & 3];
    }

    // row max (lane-local 64 keys + partner's 64 via one xor-32)
    float pm = sc[0][0];
#pragma unroll
    for (int kb = 0; kb < 4; ++kb)
#pragma unroll
      for (int r = 0; r < 16; ++r) pm = fmaxf(pm, sc[kb][r]);
    pm = fmaxf(pm, __shfl_xor(pm, 32));

    // defer-max rescale (rare after first tile)
    if (__any(pm > m_ + 8.f)) {
      float mnew = fmaxf(m_, pm);
      float fac = exp2f((m_ - mnew) * L2E);
      l_ *= fac;
#pragma unroll
      for (int r = 0; r < 16; ++r) {
        float fv = __shfl(fac, (r & 3) + 8 * (r >> 2) + 4 * hi);
#pragma unroll
        for (int nb = 0; nb < 4; ++nb) oacc[nb][r] *= fv;
      }
      m_ = mnew;
    }

    // P = exp(s - m), row sum
    const float mk = m_ * L2E;
    float rs = 0.f;
#pragma unroll
    for (int kb = 0; kb < 4; ++kb)
#pragma unroll
      for (int r = 0; r < 16; ++r) {
        float pe = exp2f(sc[kb][r] * L2E - mk);
        sc[kb][r] = pe;
        rs += pe;
      }
    rs += __shfl_xor(rs, 32);
    l_ += rs;

    // pack to bf16 pairs: pk[kb][r2] = keys kb*32 + 8*(r2>>1) + 4*hi + 2*(r2&1) + {0,1}
    u32 pk[4][8];
#pragma unroll
    for (int kb = 0; kb < 4; ++kb)
#pragma unroll
      for (int r2 = 0; r2 < 8; ++r2)
        pk[kb][r2] = (u32)f2bf(sc[kb][2 * r2]) | ((u32)f2bf(sc[kb][2 * r2 + 1]) << 16);

    // PV: for each 16-key chunk kc, build a-frag (lane&31=q, keys kc*16+hi*8+0..7)
#pragma unroll
    for (int kc = 0; kc < 8; ++kc) {
      const int kb = kc >> 1;
      const int ra = (kc & 1) * 4, rb = ra + 2;
      u32 E0 = hi ? pk[kb][ra + 0] : pk[kb][rb + 0];
      u32 E1 = hi ? pk[kb][ra + 1] : pk[kb][rb + 1];
      u32 G0 = __shfl_xor(E0, 32), G1 = __shfl_xor(E1, 32);
      u32 S0 = hi ? pk[kb][rb + 0] : pk[kb][ra + 0];
      u32 S1 = hi ? pk[kb][rb + 1] : pk[kb][ra + 1];
      union { u32 u[4]; s16x8 v; } pa;
      pa.u[0] = hi ? G0 : S0;
      pa.u[1] = hi ? G1 : S1;
      pa.u[2] = hi ? S0 : G0;
      pa.u[3] = hi ? S1 : G1;
#pragma unroll
      for (int nb = 0; nb < 4; ++nb) {
        int row = nb * 32 + q32;
        int off = row * 256 + ((kc * 32 + hi * 16) ^ ((row & 15) << 4));
        s16x8 vb = *(const s16x8*)((const char*)lV + off);
        oacc[nb] = mfma32(pa.v, vb, oacc[nb]);
      }
    }
    __syncthreads();
  }

  float inv = (m_ > -1e29f) ? (1.0f / l_) : 0.f;  // fully-masked row -> 0
  float* obase = attnO + ((size_t)(b * 1024 + qb * 128 + w * 32)) * 1024 + h * 128;
#pragma unroll
  for (int r = 0; r < 16; ++r) {
    int qr = (r & 3) + 8 * (r >> 2) + 4 * hi;
    float iv = __shfl(inv, qr);
#pragma unroll
    for (int nb = 0; nb < 4; ++nb)
      obase[(size_t)qr * 1024 + nb * 32 + q32] = oacc[nb][r] * iv;
  }
}

// ---------------------------------------------------------------------------
// fused residual + LayerNorm over 1024 cols. one block per row.
// ---------------------------------------------------------------------------
__global__ __launch_bounds__(256) void ln_fused(
    const float* __restrict__ aF, const u16* __restrict__ aBF,
    const float* __restrict__ badd, const float* __restrict__ g,
    const float* __restrict__ bt, float* __restrict__ outF,
    u16* __restrict__ outBF) {
  const int row = blockIdx.x;
  const int c = threadIdx.x << 2;
  const size_t base = (size_t)row * 1024 + c;
  float4 h;
  if (aF) {
    h = *(const float4*)(aF + base);
  } else {
    u16x4 u = *(const u16x4*)(aBF + base);
    h.x = bf2f(u[0]); h.y = bf2f(u[1]); h.z = bf2f(u[2]); h.w = bf2f(u[3]);
  }
  if (badd) {
    float4 t = *(const float4*)(badd + base);
    h.x += t.x; h.y += t.y; h.z += t.z; h.w += t.w;
  }
  float s = (h.x + h.y) + (h.z + h.w);
  float q = (h.x * h.x + h.y * h.y) + (h.z * h.z + h.w * h.w);
#pragma unroll
  for (int msk = 1; msk < 64; msk <<= 1) {
    s += __shfl_xor(s, msk);
    q += __shfl_xor(q, msk);
  }
  __shared__ float sh[8];
  const int w = threadIdx.x >> 6;
  if ((threadIdx.x & 63) == 0) { sh[w] = s; sh[4 + w] = q; }
  __syncthreads();
  s = (sh[0] + sh[1]) + (sh[2] + sh[3]);
  q = (sh[4] + sh[5]) + (sh[6] + sh[7]);
  const float mu = s * (1.f / 1024.f);
  const float var = q * (1.f / 1024.f) - mu * mu;
  const float rstd = rsqrtf(var + 1e-5f);
  const float4 gv = *(const float4*)(g + c);
  const float4 bv = *(const float4*)(bt + c);
  float4 o;
  o.x = (h.x - mu) * rstd * gv.x + bv.x;
  o.y = (h.y - mu) * rstd * gv.y + bv.y;
  o.z = (h.z - mu) * rstd * gv.z + bv.z;
  o.w = (h.w - mu) * rstd * gv.w + bv.w;
  if (outF) *(float4*)(outF + base) = o;
  if (outBF) {
    u16x4 ub; ub[0] = f2bf(o.x); ub[1] = f2bf(o.y); ub[2] = f2bf(o.z); ub[3] = f2bf(o.w);
    *(u16x4*)(outBF + base) = ub;
  }
}

// ---------------------------------------------------------------------------
extern "C" void kernel_launch(void* const* d_in, const int* in_sizes, int n_in,
                              void* d_out, int out_size, void* d_ws, size_t ws_size,
                              hipStream_t stream) {
  const float* X  = (const float*)d_in[0];
  const float* Y  = (const float*)d_in[1];
  const void*  mask = d_in[2];
  const float* Wq = (const float*)d_in[3];
  const float* bq = (const float*)d_in[4];
  const float* Wk = (const float*)d_in[5];
  const float* bk = (const float*)d_in[6];
  const float* Wv = (const float*)d_in[7];
  const float* bv = (const float*)d_in[8];
  const float* Wo = (const float*)d_in[9];
  const float* bo = (const float*)d_in[10];
  const float* g1 = (const float*)d_in[11];
  const float* b1 = (const float*)d_in[12];
  const float* g2 = (const float*)d_in[13];
  const float* b2 = (const float*)d_in[14];
  float* out = (float*)d_out;

  char* ws = (char*)d_ws;
  const size_t MB = 1024ull * 1024ull;
  u16* Xbf = (u16*)(ws + 0);          // 16MB, dead after Q-gemm -> O1bf
  u16* Ybf = (u16*)(ws + 16 * MB);    // 16MB
  u16* Qbf = (u16*)(ws + 32 * MB);    // 16MB
  u16* Kbf = (u16*)(ws + 48 * MB);    // 16MB \ dead after attn -> O1f (32MB)
  u16* Vt  = (u16*)(ws + 64 * MB);    // 16MB /
  float* attn = (float*)(ws + 80 * MB);  // 32MB, dead after LN1 -> R
  u16* Wqt = (u16*)(ws + 112 * MB);
  u16* Wkt = (u16*)(ws + 114 * MB);
  u16* Wvt = (u16*)(ws + 116 * MB);
  u16* Wot = (u16*)(ws + 118 * MB);
  float* maskb = (float*)(ws + 120 * MB);  // 32KB
  float* O1f = (float*)(ws + 48 * MB);
  u16* O1bf = Xbf;
  float* R = attn;

  prep_mask<<<dim3(32), dim3(256), 0, stream>>>((const u32*)mask, maskb);
  cvt_f2bf<<<dim3(2048), dim3(256), 0, stream>>>(X, Xbf, 2097152);
  cvt_f2bf<<<dim3(2048), dim3(256), 0, stream>>>(Y, Ybf, 2097152);
  transpose_cvt<<<dim3(32, 32, 4), dim3(32, 8), 0, stream>>>(Wq, Wk, Wv, Wo, Wqt, Wkt, Wvt, Wot);

  gemm_nt<1><<<dim3(512), dim3(256), 0, stream>>>(Xbf, Wqt, bq, nullptr, Qbf, nullptr);
  gemm_nt<1><<<dim3(512), dim3(256), 0, stream>>>(Ybf, Wkt, bk, nullptr, Kbf, nullptr);
  gemm_nt<2><<<dim3(512), dim3(256), 0, stream>>>(Ybf, Wvt, bv, nullptr, Vt, nullptr);

  attn_fwd<<<dim3(512), dim3(256), 0, stream>>>(Qbf, Kbf, Vt, maskb, attn);

  ln_fused<<<dim3(8192), dim3(256), 0, stream>>>(nullptr, Qbf, attn, g1, b1, O1f, O1bf);
  gemm_nt<3><<<dim3(512), dim3(256), 0, stream>>>(O1bf, Wot, bo, R, nullptr, O1f);
  ln_fused<<<dim3(8192), dim3(256), 0, stream>>>(R, nullptr, nullptr, g2, b2, out, nullptr);
}

// Round 3
// 186.110 us; speedup vs baseline: 1.4557x; 1.1519x over previous
//
#include <hip/hip_runtime.h>
#include <stdint.h>

// ---------------------------------------------------------------------------
// MAB block: O = LN2(O1 + relu(O1@Wo+bo)), O1 = LN1(Q + MHA(Q,K,V,mask))
// ---------------------------------------------------------------------------

typedef unsigned short u16;
typedef unsigned int u32;
typedef __attribute__((ext_vector_type(8))) short s16x8;   // bf16x8 frag (4 VGPR)
typedef __attribute__((ext_vector_type(4))) float f32x4;
typedef __attribute__((ext_vector_type(16))) float f32x16; // 32x32 MFMA C/D
typedef __attribute__((ext_vector_type(4))) u16 u16x4;

typedef __attribute__((address_space(1))) const void* as1cv;
typedef __attribute__((address_space(3))) void* as3v;

#define DEVINL __device__ __forceinline__

DEVINL u16 f2bf(float f) {
  union { float f; u32 u; } v; v.f = f;
  return (u16)((v.u + 0x7FFFu + ((v.u >> 16) & 1u)) >> 16);  // RNE
}
DEVINL float bf2f(u16 x) {
  union { u32 u; float f; } v; v.u = ((u32)x) << 16;
  return v.f;
}
DEVINL u32 cvtpk_bf16(float lo, float hi) {  // packed RNE f32x2 -> bf16x2
  u32 r;
  asm("v_cvt_pk_bf16_f32 %0, %1, %2" : "=v"(r) : "v"(lo), "v"(hi));
  return r;
}
DEVINL float fexp2(float x) {  // raw v_exp_f32 (2^x), no denormal fixup
  float r;
  asm("v_exp_f32 %0, %1" : "=v"(r) : "v"(x));
  return r;
}
DEVINL void gload_lds16(const void* g, void* l) {
  __builtin_amdgcn_global_load_lds((as1cv)g, (as3v)l, 16, 0, 0);
}
DEVINL f32x4 mfma16(s16x8 a, s16x8 b, f32x4 c) {
  return __builtin_amdgcn_mfma_f32_16x16x32_bf16(a, b, c, 0, 0, 0);
}
DEVINL f32x16 mfma32(s16x8 a, s16x8 b, f32x16 c) {
  return __builtin_amdgcn_mfma_f32_32x32x16_bf16(a, b, c, 0, 0, 0);
}

// ---------------------------------------------------------------------------
// mask prep: detect layout (bool/int/float), write pre-folded softmax bias:
// unmasked -> -8*log2e, masked -> -3e30  (p = exp2(s*scale*log2e + bias))
// ---------------------------------------------------------------------------
__global__ void prep_mask(const u32* __restrict__ mraw, float* __restrict__ maskb) {
  __shared__ int mode;
  int t = threadIdx.x;
  int fB = 0, fF = 0;
  for (int i = t; i < 2048; i += 256) {
    u32 v = mraw[i];
    if (v == 0x3F800000u) fF = 1;
    else if (v > 1u) fB = 1;
  }
  if (t == 0) mode = 0;
  __syncthreads();
  if (fB) atomicOr(&mode, 1);
  if (fF) atomicOr(&mode, 2);
  __syncthreads();
  int md = mode;
  int idx = blockIdx.x * 256 + t;
  int v;
  if (md & 1)       v = ((const unsigned char*)mraw)[idx] != 0;
  else if (md & 2)  v = ((const float*)mraw)[idx] != 0.0f;
  else              v = ((const int*)mraw)[idx] != 0;
  maskb[idx] = v ? -3e30f : -11.54156032f;
}

// f32 -> bf16 for X and Y in one launch (grid = 2 * n4 / 256)
__global__ void cvt_f2bf2(const float* __restrict__ in0, u16* __restrict__ out0,
                          const float* __restrict__ in1, u16* __restrict__ out1,
                          int n4) {
  int i = blockIdx.x * blockDim.x + threadIdx.x;
  const float* in = in0;
  u16* out = out0;
  if (i >= n4) { i -= n4; in = in1; out = out1; }
  float4 v = *(const float4*)(in + (size_t)i * 4);
  u16x4 o; o[0] = f2bf(v.x); o[1] = f2bf(v.y); o[2] = f2bf(v.z); o[3] = f2bf(v.w);
  *(u16x4*)(out + (size_t)i * 4) = o;
}

__global__ void transpose_cvt(const float* __restrict__ W0, const float* __restrict__ W1,
                              const float* __restrict__ W2, const float* __restrict__ W3,
                              u16* __restrict__ T0, u16* __restrict__ T1,
                              u16* __restrict__ T2, u16* __restrict__ T3) {
  const float* W = (blockIdx.z == 0) ? W0 : (blockIdx.z == 1) ? W1 : (blockIdx.z == 2) ? W2 : W3;
  u16* T = (blockIdx.z == 0) ? T0 : (blockIdx.z == 1) ? T1 : (blockIdx.z == 2) ? T2 : T3;
  __shared__ float tile[32][33];
  int tx = threadIdx.x, ty = threadIdx.y;
  int N0 = blockIdx.x << 5, K0 = blockIdx.y << 5;
#pragma unroll
  for (int i = 0; i < 4; ++i)
    tile[ty + i * 8][tx] = W[(size_t)(K0 + ty + i * 8) * 1024 + N0 + tx];
  __syncthreads();
#pragma unroll
  for (int i = 0; i < 4; ++i)
    T[(size_t)(N0 + ty + i * 8) * 1024 + K0 + tx] = f2bf(tile[tx][ty + i * 8]);
}

// ---------------------------------------------------------------------------
// NT GEMM: 128x128 tile, BK=64, 4 waves, mfma 16x16x32 bf16.
// MODE 1: outBF = bf16(acc+bias)
// MODE 2: outBF transposed Vt[(b*1024+n)][m%1024]
// MODE 3: outF = bf2f(residBF) + relu(acc+bias)
// ---------------------------------------------------------------------------
template <int MODE>
__global__ __launch_bounds__(256, 2) void gemm_nt(
    const u16* __restrict__ A, const u16* __restrict__ Bt,
    const float* __restrict__ bias, float* __restrict__ outF,
    u16* __restrict__ outBF, const u16* __restrict__ residBF) {
  __shared__ u16 lA[128 * 64];
  __shared__ u16 lB[128 * 64];

  const int id = blockIdx.x;
  const int cpx = gridDim.x >> 3;
  const int swz = (id & 7) * cpx + (id >> 3);
  const int mb = swz >> 3;
  const int nb = swz & 7;

  const int tid = threadIdx.x;
  const int w = tid >> 6, l = tid & 63;
  const int wm = w >> 1, wn = w & 1;
  const int lrow = l & 15, lk = l >> 4;

  const int sr = l >> 3;
  const int scol = ((l & 7) << 4) ^ (sr << 4);
  const char* gA = (const char*)A + (size_t)(mb * 128) * 2048;
  const char* gB = (const char*)Bt + (size_t)(nb * 128) * 2048;

  f32x4 acc[4][4];
#pragma unroll
  for (int i = 0; i < 4; ++i)
#pragma unroll
    for (int j = 0; j < 4; ++j) acc[i][j] = f32x4{0.f, 0.f, 0.f, 0.f};

  for (int kt = 0; kt < 16; ++kt) {
    const int kb = kt * 128;
#pragma unroll
    for (int c = 0; c < 4; ++c) {
      int row = (w * 4 + c) * 8 + sr;
      gload_lds16(gA + (size_t)row * 2048 + kb + scol, (char*)lA + (w * 4 + c) * 1024);
      gload_lds16(gB + (size_t)row * 2048 + kb + scol, (char*)lB + (w * 4 + c) * 1024);
    }
    __syncthreads();
#pragma unroll
    for (int kc = 0; kc < 2; ++kc) {
      s16x8 af[4], bfr[4];
#pragma unroll
      for (int mi = 0; mi < 4; ++mi) {
        int row = wm * 64 + mi * 16 + lrow;
        int off = row * 128 + ((lk * 16 + kc * 64) ^ ((row & 7) << 4));
        af[mi] = *(const s16x8*)((const char*)lA + off);
      }
#pragma unroll
      for (int ni = 0; ni < 4; ++ni) {
        int row = wn * 64 + ni * 16 + lrow;
        int off = row * 128 + ((lk * 16 + kc * 64) ^ ((row & 7) << 4));
        bfr[ni] = *(const s16x8*)((const char*)lB + off);
      }
      __builtin_amdgcn_s_setprio(1);
#pragma unroll
      for (int mi = 0; mi < 4; ++mi)
#pragma unroll
        for (int ni = 0; ni < 4; ++ni)
          acc[mi][ni] = mfma16(af[mi], bfr[ni], acc[mi][ni]);
      __builtin_amdgcn_s_setprio(0);
    }
    __syncthreads();
  }

  const int growb = mb * 128 + wm * 64;
  const int gcolb = nb * 128 + wn * 64;
  float bs[4];
#pragma unroll
  for (int ni = 0; ni < 4; ++ni) bs[ni] = bias[gcolb + ni * 16 + lrow];

#pragma unroll
  for (int mi = 0; mi < 4; ++mi) {
    const int grow0 = growb + mi * 16 + lk * 4;
#pragma unroll
    for (int ni = 0; ni < 4; ++ni) {
      const int gcol = gcolb + ni * 16 + lrow;
      if (MODE == 2) {
        u16x4 pk;
#pragma unroll
        for (int r = 0; r < 4; ++r) pk[r] = f2bf(acc[mi][ni][r] + bs[ni]);
        size_t flat = ((size_t)((grow0 >> 10) << 10) + gcol) * 1024 + (grow0 & 1023);
        *(u16x4*)(outBF + flat) = pk;
      } else {
#pragma unroll
        for (int r = 0; r < 4; ++r) {
          float v = acc[mi][ni][r] + bs[ni];
          size_t idx = (size_t)(grow0 + r) * 1024 + gcol;
          if (MODE == 1) { outBF[idx] = f2bf(v); }
          if (MODE == 3) { outF[idx] = bf2f(residBF[idx]) + fmaxf(v, 0.f); }
        }
      }
    }
  }
}

// ---------------------------------------------------------------------------
// flash attention v3: swapped QK^T on 32x32x16 MFMA, STATIC-max softmax
// (m=8: p = exp2(fma(s_raw, scale*log2e, bias)) with bias pre-folded in LDS;
// masked keys -> bias=-3e30 -> p=0 exactly), cvt_pk bf16 packing, bf16 out.
// KVBLK=128, QBLK=128 (4 waves x 32 q). grid 512; bh pinned per XCD.
// ---------------------------------------------------------------------------
__global__ __launch_bounds__(256, 2) void attn_fwd(
    const u16* __restrict__ Qbf, const u16* __restrict__ Kbf,
    const u16* __restrict__ Vt, const float* __restrict__ maskb,
    u16* __restrict__ attnO) {
  __shared__ u16 lK[128 * 128];
  __shared__ u16 lV[128 * 128];
  __shared__ float lM[1024];

  const int id = blockIdx.x;
  const int xcd = id & 7, seq = id >> 3;
  const int bh = xcd * 8 + (seq >> 3);   // all qb of a bh stay on one XCD
  const int qb = seq & 7;
  const int b = bh >> 3, h = bh & 7;
  const int tid = threadIdx.x;
  const int w = tid >> 6, l = tid & 63;
  const int q32 = l & 31, hi = l >> 5;

  // Q fragments: B-operand, lane&31 = q-row
  const u16* Qrow = Qbf + ((size_t)(b * 1024 + qb * 128 + w * 32 + q32)) * 1024 + h * 128;
  s16x8 qf[8];
#pragma unroll
  for (int dc = 0; dc < 8; ++dc) qf[dc] = *(const s16x8*)(Qrow + dc * 16 + hi * 8);

  const char* gK = (const char*)(Kbf + ((size_t)(b * 1024)) * 1024 + h * 128);
  const char* gV = (const char*)(Vt + ((size_t)(b * 1024 + h * 128)) * 1024);
  const float* mrow = maskb + b * 1024;

  // stage mask bias row into LDS once (wave 0; first in-loop barrier covers it)
  if (w == 0) {
#pragma unroll
    for (int c = 0; c < 4; ++c)
      gload_lds16(mrow + c * 256 + l * 4, (char*)lM + c * 1024);
  }

  float l_ = 0.f;
  f32x16 oacc[4];
#pragma unroll
  for (int i = 0; i < 4; ++i)
#pragma unroll
    for (int r = 0; r < 16; ++r) oacc[i][r] = 0.f;

  const int sr = l >> 4, slot = l & 15;
  const float SCL = 0.04508422f;  // (1/32) * log2(e)

  for (int t = 0; t < 8; ++t) {
    const int kbase = t * 128;
#pragma unroll
    for (int c = 0; c < 8; ++c) {
      int row = (w * 8 + c) * 4 + sr;
      int scol = (slot << 4) ^ ((row & 15) << 4);
      gload_lds16(gK + (size_t)(kbase + row) * 2048 + scol, (char*)lK + (w * 8 + c) * 1024);
      gload_lds16(gV + (size_t)row * 2048 + kbase * 2 + scol, (char*)lV + (w * 8 + c) * 1024);
    }
    __syncthreads();

    // S^T = K Q^T : lane holds col q=l&31, rows key = kb*32 + (r&3)+8*(r>>2)+4*hi
    f32x16 sc[4];
#pragma unroll
    for (int kb = 0; kb < 4; ++kb)
#pragma unroll
      for (int r = 0; r < 16; ++r) sc[kb][r] = 0.f;
    __builtin_amdgcn_s_setprio(1);
#pragma unroll
    for (int dc = 0; dc < 8; ++dc) {
#pragma unroll
      for (int kb = 0; kb < 4; ++kb) {
        int row = kb * 32 + q32;
        int off = row * 256 + ((dc * 32 + hi * 16) ^ ((row & 15) << 4));
        s16x8 kf = *(const s16x8*)((const char*)lK + off);
        sc[kb] = mfma32(kf, qf[dc], sc[kb]);
      }
    }
    __builtin_amdgcn_s_setprio(0);

    // p = exp2(s*SCL + bias) ; bias from LDS (broadcast within half-wave)
    float rs = 0.f;
#pragma unroll
    for (int kb = 0; kb < 4; ++kb) {
      const char* lMb = (const char*)lM + (size_t)(kbase + kb * 32 + hi * 4) * 4;
      f32x4 mv0 = *(const f32x4*)(lMb + 0);
      f32x4 mv1 = *(const f32x4*)(lMb + 32);
      f32x4 mv2 = *(const f32x4*)(lMb + 64);
      f32x4 mv3 = *(const f32x4*)(lMb + 96);
#pragma unroll
      for (int r = 0; r < 16; ++r) {
        float mb_ = (r < 4) ? mv0[r & 3] : (r < 8) ? mv1[r & 3] : (r < 12) ? mv2[r & 3] : mv3[r & 3];
        float pe = fexp2(fmaf(sc[kb][r], SCL, mb_));
        sc[kb][r] = pe;
        rs += pe;
      }
    }
    rs += __shfl_xor(rs, 32);
    l_ += rs;

    // pack to bf16 pairs: pk[kb][r2] = keys kb*32 + 8*(r2>>1) + 4*hi + 2*(r2&1) + {0,1}
    u32 pk[4][8];
#pragma unroll
    for (int kb = 0; kb < 4; ++kb)
#pragma unroll
      for (int r2 = 0; r2 < 8; ++r2)
        pk[kb][r2] = cvtpk_bf16(sc[kb][2 * r2], sc[kb][2 * r2 + 1]);

    // PV: build A-frag per 16-key chunk via one xor-32 pair exchange
#pragma unroll
    for (int kc = 0; kc < 8; ++kc) {
      const int kb = kc >> 1;
      const int ra = (kc & 1) * 4, rb = ra + 2;
      u32 E0 = hi ? pk[kb][ra + 0] : pk[kb][rb + 0];
      u32 E1 = hi ? pk[kb][ra + 1] : pk[kb][rb + 1];
      u32 G0 = __shfl_xor(E0, 32), G1 = __shfl_xor(E1, 32);
      u32 S0 = hi ? pk[kb][rb + 0] : pk[kb][ra + 0];
      u32 S1 = hi ? pk[kb][rb + 1] : pk[kb][ra + 1];
      union { u32 u[4]; s16x8 v; } pa;
      pa.u[0] = hi ? G0 : S0;
      pa.u[1] = hi ? G1 : S1;
      pa.u[2] = hi ? S0 : G0;
      pa.u[3] = hi ? S1 : G1;
      __builtin_amdgcn_s_setprio(1);
#pragma unroll
      for (int nb = 0; nb < 4; ++nb) {
        int row = nb * 32 + q32;
        int off = row * 256 + ((kc * 32 + hi * 16) ^ ((row & 15) << 4));
        s16x8 vb = *(const s16x8*)((const char*)lV + off);
        oacc[nb] = mfma32(pa.v, vb, oacc[nb]);
      }
      __builtin_amdgcn_s_setprio(0);
    }
    __syncthreads();
  }

  rs_done:;
  float inv = (l_ > 1e-20f) ? (1.0f / l_) : 0.f;  // fully-masked row -> 0
  u16* obase = attnO + ((size_t)(b * 1024 + qb * 128 + w * 32)) * 1024 + h * 128;
#pragma unroll
  for (int r = 0; r < 16; ++r) {
    int qr = (r & 3) + 8 * (r >> 2) + 4 * hi;
    float iv = __shfl(inv, qr);
#pragma unroll
    for (int nb = 0; nb < 4; ++nb)
      obase[(size_t)qr * 1024 + nb * 32 + q32] = f2bf(oacc[nb][r] * iv);
  }
}

// ---------------------------------------------------------------------------
// fused residual + LayerNorm over 1024 cols. one block per row.
// h = (aF ? aF : bf2f(aBF)) + (baddBF ? bf2f(baddBF) : 0); out = LN(h)*g + b
// ---------------------------------------------------------------------------
__global__ __launch_bounds__(256) void ln_fused(
    const float* __restrict__ aF, const u16* __restrict__ aBF,
    const u16* __restrict__ baddBF, const float* __restrict__ g,
    const float* __restrict__ bt, float* __restrict__ outF,
    u16* __restrict__ outBF) {
  const int row = blockIdx.x;
  const int c = threadIdx.x << 2;
  const size_t base = (size_t)row * 1024 + c;
  float4 h;
  if (aF) {
    h = *(const float4*)(aF + base);
  } else {
    u16x4 u = *(const u16x4*)(aBF + base);
    h.x = bf2f(u[0]); h.y = bf2f(u[1]); h.z = bf2f(u[2]); h.w = bf2f(u[3]);
  }
  if (baddBF) {
    u16x4 u = *(const u16x4*)(baddBF + base);
    h.x += bf2f(u[0]); h.y += bf2f(u[1]); h.z += bf2f(u[2]); h.w += bf2f(u[3]);
  }
  float s = (h.x + h.y) + (h.z + h.w);
  float q = (h.x * h.x + h.y * h.y) + (h.z * h.z + h.w * h.w);
#pragma unroll
  for (int msk = 1; msk < 64; msk <<= 1) {
    s += __shfl_xor(s, msk);
    q += __shfl_xor(q, msk);
  }
  __shared__ float sh[8];
  const int w = threadIdx.x >> 6;
  if ((threadIdx.x & 63) == 0) { sh[w] = s; sh[4 + w] = q; }
  __syncthreads();
  s = (sh[0] + sh[1]) + (sh[2] + sh[3]);
  q = (sh[4] + sh[5]) + (sh[6] + sh[7]);
  const float mu = s * (1.f / 1024.f);
  const float var = q * (1.f / 1024.f) - mu * mu;
  const float rstd = rsqrtf(var + 1e-5f);
  const float4 gv = *(const float4*)(g + c);
  const float4 bv = *(const float4*)(bt + c);
  float4 o;
  o.x = (h.x - mu) * rstd * gv.x + bv.x;
  o.y = (h.y - mu) * rstd * gv.y + bv.y;
  o.z = (h.z - mu) * rstd * gv.z + bv.z;
  o.w = (h.w - mu) * rstd * gv.w + bv.w;
  if (outF) *(float4*)(outF + base) = o;
  if (outBF) {
    u16x4 ub; ub[0] = f2bf(o.x); ub[1] = f2bf(o.y); ub[2] = f2bf(o.z); ub[3] = f2bf(o.w);
    *(u16x4*)(outBF + base) = ub;
  }
}

// ---------------------------------------------------------------------------
extern "C" void kernel_launch(void* const* d_in, const int* in_sizes, int n_in,
                              void* d_out, int out_size, void* d_ws, size_t ws_size,
                              hipStream_t stream) {
  const float* X  = (const float*)d_in[0];
  const float* Y  = (const float*)d_in[1];
  const void*  mask = d_in[2];
  const float* Wq = (const float*)d_in[3];
  const float* bq = (const float*)d_in[4];
  const float* Wk = (const float*)d_in[5];
  const float* bk = (const float*)d_in[6];
  const float* Wv = (const float*)d_in[7];
  const float* bv = (const float*)d_in[8];
  const float* Wo = (const float*)d_in[9];
  const float* bo = (const float*)d_in[10];
  const float* g1 = (const float*)d_in[11];
  const float* b1 = (const float*)d_in[12];
  const float* g2 = (const float*)d_in[13];
  const float* b2 = (const float*)d_in[14];
  float* out = (float*)d_out;

  char* ws = (char*)d_ws;
  const size_t MB = 1024ull * 1024ull;
  u16* Xbf    = (u16*)(ws + 0);         // 16MB, dead after Q-gemm -> O1bf
  u16* Ybf    = (u16*)(ws + 16 * MB);   // 16MB
  u16* Qbf    = (u16*)(ws + 32 * MB);   // 16MB (alive through LN1)
  u16* Kbf    = (u16*)(ws + 48 * MB);   // 16MB \ dead after attn -> R (32MB f32)
  u16* Vt     = (u16*)(ws + 64 * MB);   // 16MB /
  u16* attnbf = (u16*)(ws + 80 * MB);   // 16MB, dead after LN1
  u16* Wqt = (u16*)(ws + 112 * MB);
  u16* Wkt = (u16*)(ws + 114 * MB);
  u16* Wvt = (u16*)(ws + 116 * MB);
  u16* Wot = (u16*)(ws + 118 * MB);
  float* maskb = (float*)(ws + 120 * MB);  // 32KB
  float* R = (float*)(ws + 48 * MB);       // 32MB (Kbf+Vt reuse)
  u16* O1bf = Xbf;

  prep_mask<<<dim3(32), dim3(256), 0, stream>>>((const u32*)mask, maskb);
  cvt_f2bf2<<<dim3(16384), dim3(256), 0, stream>>>(X, Xbf, Y, Ybf, 2097152);
  transpose_cvt<<<dim3(32, 32, 4), dim3(32, 8), 0, stream>>>(Wq, Wk, Wv, Wo, Wqt, Wkt, Wvt, Wot);

  gemm_nt<1><<<dim3(512), dim3(256), 0, stream>>>(Xbf, Wqt, bq, nullptr, Qbf, nullptr);
  gemm_nt<1><<<dim3(512), dim3(256), 0, stream>>>(Ybf, Wkt, bk, nullptr, Kbf, nullptr);
  gemm_nt<2><<<dim3(512), dim3(256), 0, stream>>>(Ybf, Wvt, bv, nullptr, Vt, nullptr);

  attn_fwd<<<dim3(512), dim3(256), 0, stream>>>(Qbf, Kbf, Vt, maskb, attnbf);

  ln_fused<<<dim3(8192), dim3(256), 0, stream>>>(nullptr, Qbf, attnbf, g1, b1, nullptr, O1bf);
  gemm_nt<3><<<dim3(512), dim3(256), 0, stream>>>(O1bf, Wot, bo, R, nullptr, O1bf);
  ln_fused<<<dim3(8192), dim3(256), 0, stream>>>(R, nullptr, nullptr, g2, b2, out, nullptr);
}

// Round 4
// 182.918 us; speedup vs baseline: 1.4811x; 1.0175x over previous
//
#include <hip/hip_runtime.h>
#include <stdint.h>

// ---------------------------------------------------------------------------
// MAB block: O = LN2(O1 + relu(O1@Wo+bo)), O1 = LN1(Q + MHA(Q,K,V,mask))
// ---------------------------------------------------------------------------

typedef unsigned short u16;
typedef unsigned int u32;
typedef __attribute__((ext_vector_type(8))) short s16x8;   // bf16x8 frag (4 VGPR)
typedef __attribute__((ext_vector_type(4))) float f32x4;
typedef __attribute__((ext_vector_type(16))) float f32x16; // 32x32 MFMA C/D
typedef __attribute__((ext_vector_type(4))) u16 u16x4;

typedef __attribute__((address_space(1))) const void* as1cv;
typedef __attribute__((address_space(3))) void* as3v;

#define DEVINL __device__ __forceinline__

DEVINL u16 f2bf(float f) {
  union { float f; u32 u; } v; v.f = f;
  return (u16)((v.u + 0x7FFFu + ((v.u >> 16) & 1u)) >> 16);  // RNE
}
DEVINL float bf2f(u16 x) {
  union { u32 u; float f; } v; v.u = ((u32)x) << 16;
  return v.f;
}
DEVINL u32 cvtpk_bf16(float lo, float hi) {  // packed RNE f32x2 -> bf16x2
  u32 r;
  asm("v_cvt_pk_bf16_f32 %0, %1, %2" : "=v"(r) : "v"(lo), "v"(hi));
  return r;
}
DEVINL float fexp2(float x) {  // raw v_exp_f32 (2^x)
  float r;
  asm("v_exp_f32 %0, %1" : "=v"(r) : "v"(x));
  return r;
}
DEVINL void gload_lds16(const void* g, void* l) {
  __builtin_amdgcn_global_load_lds((as1cv)g, (as3v)l, 16, 0, 0);
}
DEVINL f32x4 mfma16(s16x8 a, s16x8 b, f32x4 c) {
  return __builtin_amdgcn_mfma_f32_16x16x32_bf16(a, b, c, 0, 0, 0);
}
DEVINL f32x16 mfma32(s16x8 a, s16x8 b, f32x16 c) {
  return __builtin_amdgcn_mfma_f32_32x32x16_bf16(a, b, c, 0, 0, 0);
}

// ---------------------------------------------------------------------------
// mask prep: detect layout (bool/int/float), write pre-folded softmax bias:
// unmasked -> -8*log2e, masked -> -3e30  (p = exp2(s*scale*log2e + bias))
// ---------------------------------------------------------------------------
__global__ void prep_mask(const u32* __restrict__ mraw, float* __restrict__ maskb) {
  __shared__ int mode;
  int t = threadIdx.x;
  int fB = 0, fF = 0;
  for (int i = t; i < 2048; i += 256) {
    u32 v = mraw[i];
    if (v == 0x3F800000u) fF = 1;
    else if (v > 1u) fB = 1;
  }
  if (t == 0) mode = 0;
  __syncthreads();
  if (fB) atomicOr(&mode, 1);
  if (fF) atomicOr(&mode, 2);
  __syncthreads();
  int md = mode;
  int idx = blockIdx.x * 256 + t;
  int v;
  if (md & 1)       v = ((const unsigned char*)mraw)[idx] != 0;
  else if (md & 2)  v = ((const float*)mraw)[idx] != 0.0f;
  else              v = ((const int*)mraw)[idx] != 0;
  maskb[idx] = v ? -3e30f : -11.54156032f;
}

// f32 -> bf16 for X and Y in one launch
__global__ void cvt_f2bf2(const float* __restrict__ in0, u16* __restrict__ out0,
                          const float* __restrict__ in1, u16* __restrict__ out1,
                          int n4) {
  int i = blockIdx.x * blockDim.x + threadIdx.x;
  const float* in = in0;
  u16* out = out0;
  if (i >= n4) { i -= n4; in = in1; out = out1; }
  float4 v = *(const float4*)(in + (size_t)i * 4);
  u16x4 o; o[0] = f2bf(v.x); o[1] = f2bf(v.y); o[2] = f2bf(v.z); o[3] = f2bf(v.w);
  *(u16x4*)(out + (size_t)i * 4) = o;
}

__global__ void transpose_cvt(const float* __restrict__ W0, const float* __restrict__ W1,
                              const float* __restrict__ W2, const float* __restrict__ W3,
                              u16* __restrict__ T0, u16* __restrict__ T1,
                              u16* __restrict__ T2, u16* __restrict__ T3) {
  const float* W = (blockIdx.z == 0) ? W0 : (blockIdx.z == 1) ? W1 : (blockIdx.z == 2) ? W2 : W3;
  u16* T = (blockIdx.z == 0) ? T0 : (blockIdx.z == 1) ? T1 : (blockIdx.z == 2) ? T2 : T3;
  __shared__ float tile[32][33];
  int tx = threadIdx.x, ty = threadIdx.y;
  int N0 = blockIdx.x << 5, K0 = blockIdx.y << 5;
#pragma unroll
  for (int i = 0; i < 4; ++i)
    tile[ty + i * 8][tx] = W[(size_t)(K0 + ty + i * 8) * 1024 + N0 + tx];
  __syncthreads();
#pragma unroll
  for (int i = 0; i < 4; ++i)
    T[(size_t)(N0 + ty + i * 8) * 1024 + K0 + tx] = f2bf(tile[tx][ty + i * 8]);
}

// ---------------------------------------------------------------------------
// NT GEMM: 128x128 tile, BK=64, 4 waves, mfma 16x16x32 bf16.
// MODE 1: outBF = bf16(acc+bias)
// MODE 2: outBF transposed Vt[(b*1024+n)][m%1024]
// MODE 3: outBF = bf16(bf2f(residBF) + relu(acc+bias))
// ---------------------------------------------------------------------------
template <int MODE>
__global__ __launch_bounds__(256, 2) void gemm_nt(
    const u16* __restrict__ A, const u16* __restrict__ Bt,
    const float* __restrict__ bias, float* __restrict__ outF,
    u16* __restrict__ outBF, const u16* __restrict__ residBF) {
  __shared__ u16 lA[128 * 64];
  __shared__ u16 lB[128 * 64];

  const int id = blockIdx.x;
  const int cpx = gridDim.x >> 3;
  const int swz = (id & 7) * cpx + (id >> 3);
  const int mb = swz >> 3;
  const int nb = swz & 7;

  const int tid = threadIdx.x;
  const int w = tid >> 6, l = tid & 63;
  const int wm = w >> 1, wn = w & 1;
  const int lrow = l & 15, lk = l >> 4;

  const int sr = l >> 3;
  const int scol = ((l & 7) << 4) ^ (sr << 4);
  const char* gA = (const char*)A + (size_t)(mb * 128) * 2048;
  const char* gB = (const char*)Bt + (size_t)(nb * 128) * 2048;

  f32x4 acc[4][4];
#pragma unroll
  for (int i = 0; i < 4; ++i)
#pragma unroll
    for (int j = 0; j < 4; ++j) acc[i][j] = f32x4{0.f, 0.f, 0.f, 0.f};

  for (int kt = 0; kt < 16; ++kt) {
    const int kb = kt * 128;
#pragma unroll
    for (int c = 0; c < 4; ++c) {
      int row = (w * 4 + c) * 8 + sr;
      gload_lds16(gA + (size_t)row * 2048 + kb + scol, (char*)lA + (w * 4 + c) * 1024);
      gload_lds16(gB + (size_t)row * 2048 + kb + scol, (char*)lB + (w * 4 + c) * 1024);
    }
    __syncthreads();
#pragma unroll
    for (int kc = 0; kc < 2; ++kc) {
      s16x8 af[4], bfr[4];
#pragma unroll
      for (int mi = 0; mi < 4; ++mi) {
        int row = wm * 64 + mi * 16 + lrow;
        int off = row * 128 + ((lk * 16 + kc * 64) ^ ((row & 7) << 4));
        af[mi] = *(const s16x8*)((const char*)lA + off);
      }
#pragma unroll
      for (int ni = 0; ni < 4; ++ni) {
        int row = wn * 64 + ni * 16 + lrow;
        int off = row * 128 + ((lk * 16 + kc * 64) ^ ((row & 7) << 4));
        bfr[ni] = *(const s16x8*)((const char*)lB + off);
      }
      __builtin_amdgcn_s_setprio(1);
#pragma unroll
      for (int mi = 0; mi < 4; ++mi)
#pragma unroll
        for (int ni = 0; ni < 4; ++ni)
          acc[mi][ni] = mfma16(af[mi], bfr[ni], acc[mi][ni]);
      __builtin_amdgcn_s_setprio(0);
    }
    __syncthreads();
  }

  const int growb = mb * 128 + wm * 64;
  const int gcolb = nb * 128 + wn * 64;
  float bs[4];
#pragma unroll
  for (int ni = 0; ni < 4; ++ni) bs[ni] = bias[gcolb + ni * 16 + lrow];

#pragma unroll
  for (int mi = 0; mi < 4; ++mi) {
    const int grow0 = growb + mi * 16 + lk * 4;
#pragma unroll
    for (int ni = 0; ni < 4; ++ni) {
      const int gcol = gcolb + ni * 16 + lrow;
      if (MODE == 2) {
        u16x4 pk;
#pragma unroll
        for (int r = 0; r < 4; ++r) pk[r] = f2bf(acc[mi][ni][r] + bs[ni]);
        size_t flat = ((size_t)((grow0 >> 10) << 10) + gcol) * 1024 + (grow0 & 1023);
        *(u16x4*)(outBF + flat) = pk;
      } else {
#pragma unroll
        for (int r = 0; r < 4; ++r) {
          float v = acc[mi][ni][r] + bs[ni];
          size_t idx = (size_t)(grow0 + r) * 1024 + gcol;
          if (MODE == 1) { outBF[idx] = f2bf(v); }
          if (MODE == 3) { outBF[idx] = f2bf(bf2f(residBF[idx]) + fmaxf(v, 0.f)); }
        }
      }
    }
  }
}

// ---------------------------------------------------------------------------
// flash attention v4: swapped QK^T on 32x32x16 MFMA, static-max softmax,
// KVBLK=64 double-buffered (stage t+1 issued before compute t -> latency
// hidden under compute), loop-invariant lane addresses + immediate offsets,
// permlane32_swap PV fragment exchange. grid 512; bh pinned per XCD.
// ---------------------------------------------------------------------------
__global__ __launch_bounds__(256, 2) void attn_fwd(
    const u16* __restrict__ Qbf, const u16* __restrict__ Kbf,
    const u16* __restrict__ Vt, const float* __restrict__ maskb,
    u16* __restrict__ attnO) {
  __shared__ u16 lK[2][64 * 128];    // [buf][key][d]  rows 256B, swz (key&15)<<4
  __shared__ u16 lV[2][128 * 64];    // [buf][d][key]  rows 128B, swz (d&7)<<4
  __shared__ float lM[1024];         // pre-folded softmax bias

  const int id = blockIdx.x;
  const int xcd = id & 7, seq = id >> 3;
  const int bh = xcd * 8 + (seq >> 3);   // all qb of a bh stay on one XCD
  const int qb = seq & 7;
  const int b = bh >> 3, h = bh & 7;
  const int tid = threadIdx.x;
  const int w = tid >> 6, l = tid & 63;
  const int q32 = l & 31, hi = l >> 5;

  // Q fragments: B-operand, lane&31 = q-row
  const u16* Qrow = Qbf + ((size_t)(b * 1024 + qb * 128 + w * 32 + q32)) * 1024 + h * 128;
  s16x8 qf[8];
#pragma unroll
  for (int dc = 0; dc < 8; ++dc) qf[dc] = *(const s16x8*)(Qrow + dc * 16 + hi * 8);

  // staging source lane offsets (pre-swizzled; LDS dst is linear)
  const int srK = l >> 4, slK = l & 15;
  const int srV = l >> 3, slV = l & 7;
  int soK[4], soV[4];
#pragma unroll
  for (int c = 0; c < 4; ++c) {
    int rowK = (w * 4 + c) * 4 + srK;
    soK[c] = rowK * 2048 + ((slK << 4) ^ ((rowK & 15) << 4));
    int dV = (w * 4 + c) * 8 + srV;
    soV[c] = dV * 2048 + ((slV << 4) ^ ((dV & 7) << 4));
  }
  const char* pgK = (const char*)(Kbf + ((size_t)(b * 1024)) * 1024 + h * 128);
  const char* pgV = (const char*)(Vt + ((size_t)(b * 1024 + h * 128)) * 1024);

  // ds_read lane offsets (loop-invariant; buf/kb/nb become immediates)
  int loK[8], loV[4];
#pragma unroll
  for (int c = 0; c < 8; ++c)
    loK[c] = q32 * 256 + ((c * 32 + hi * 16) ^ ((q32 & 15) << 4));
#pragma unroll
  for (int c = 0; c < 4; ++c)
    loV[c] = q32 * 128 + ((c * 32 + hi * 16) ^ ((q32 & 7) << 4));

  // stage mask bias row (wave 0); prologue barrier covers it
  if (w == 0) {
#pragma unroll
    for (int c = 0; c < 4; ++c)
      gload_lds16(maskb + b * 1024 + c * 256 + l * 4, (char*)lM + c * 1024);
  }

  float l_ = 0.f;
  f32x16 oacc[4];
#pragma unroll
  for (int i = 0; i < 4; ++i)
#pragma unroll
    for (int r = 0; r < 16; ++r) oacc[i][r] = 0.f;

  const float SCL = 0.04508422f;  // (1/32) * log2(e)

#define ATT_STAGE(NXT, TN)                                                    \
  {                                                                           \
    const char* pk_ = pgK + (size_t)(TN)*131072;                              \
    const char* pv_ = pgV + (size_t)(TN)*128;                                 \
    _Pragma("unroll")                                                         \
    for (int c = 0; c < 4; ++c) {                                             \
      gload_lds16(pk_ + soK[c], (char*)lK[NXT] + w * 4096 + c * 1024);        \
      gload_lds16(pv_ + soV[c], (char*)lV[NXT] + w * 4096 + c * 1024);        \
    }                                                                         \
  }

#define ATT_COMPUTE(CUR, PMT)                                                 \
  {                                                                           \
    f32x16 sc[2];                                                             \
    _Pragma("unroll")                                                         \
    for (int kb = 0; kb < 2; ++kb)                                            \
      _Pragma("unroll")                                                       \
      for (int r = 0; r < 16; ++r) sc[kb][r] = 0.f;                           \
    __builtin_amdgcn_s_setprio(1);                                            \
    _Pragma("unroll")                                                         \
    for (int dc = 0; dc < 8; ++dc) {                                          \
      _Pragma("unroll")                                                       \
      for (int kb = 0; kb < 2; ++kb) {                                        \
        s16x8 kf = *(const s16x8*)((const char*)lK[CUR] + loK[dc] + kb * 8192); \
        sc[kb] = mfma32(kf, qf[dc], sc[kb]);                                  \
      }                                                                       \
    }                                                                         \
    __builtin_amdgcn_s_setprio(0);                                            \
    float rs = 0.f;                                                           \
    _Pragma("unroll")                                                         \
    for (int kb = 0; kb < 2; ++kb) {                                          \
      f32x4 mv[4];                                                            \
      _Pragma("unroll")                                                       \
      for (int g = 0; g < 4; ++g)                                             \
        mv[g] = *(const f32x4*)((PMT) + kb * 128 + g * 32);                   \
      _Pragma("unroll")                                                       \
      for (int r = 0; r < 16; ++r) {                                          \
        float pe = fexp2(fmaf(sc[kb][r], SCL, mv[r >> 2][r & 3]));            \
        sc[kb][r] = pe;                                                       \
        rs += pe;                                                             \
      }                                                                       \
    }                                                                         \
    rs += __shfl_xor(rs, 32);                                                 \
    l_ += rs;                                                                 \
    u32 pk[2][8];                                                             \
    _Pragma("unroll")                                                         \
    for (int kb = 0; kb < 2; ++kb)                                            \
      _Pragma("unroll")                                                       \
      for (int r2 = 0; r2 < 8; ++r2)                                          \
        pk[kb][r2] = cvtpk_bf16(sc[kb][2 * r2], sc[kb][2 * r2 + 1]);          \
    _Pragma("unroll")                                                         \
    for (int kc = 0; kc < 4; ++kc) {                                          \
      const int kb = kc >> 1;                                                 \
      const int ra = (kc & 1) * 4;                                            \
      u32 x0 = pk[kb][ra + 0], y0 = pk[kb][ra + 2];                           \
      u32 x1 = pk[kb][ra + 1], y1 = pk[kb][ra + 3];                           \
      asm("v_permlane32_swap_b32 %0, %1" : "+v"(x0), "+v"(y0));               \
      asm("v_permlane32_swap_b32 %0, %1" : "+v"(x1), "+v"(y1));               \
      union { u32 u[4]; s16x8 v; } pa;                                        \
      pa.u[0] = x0; pa.u[1] = x1; pa.u[2] = y0; pa.u[3] = y1;                 \
      __builtin_amdgcn_s_setprio(1);                                          \
      _Pragma("unroll")                                                       \
      for (int nb = 0; nb < 4; ++nb) {                                        \
        s16x8 vb = *(const s16x8*)((const char*)lV[CUR] + loV[kc] + nb * 4096); \
        oacc[nb] = mfma32(pa.v, vb, oacc[nb]);                                \
      }                                                                       \
      __builtin_amdgcn_s_setprio(0);                                          \
    }                                                                         \
  }

  const char* pM0 = (const char*)lM + hi * 16;

  ATT_STAGE(0, 0);
  __syncthreads();
  for (int it = 0; it < 7; ++it) {
    const char* pMa = pM0 + it * 512;
    ATT_STAGE(1, 2 * it + 1);
    ATT_COMPUTE(0, pMa);
    __syncthreads();
    ATT_STAGE(0, 2 * it + 2);
    ATT_COMPUTE(1, pMa + 256);
    __syncthreads();
  }
  {
    const char* pMa = pM0 + 7 * 512;
    ATT_STAGE(1, 15);
    ATT_COMPUTE(0, pMa);
    __syncthreads();
    ATT_COMPUTE(1, pMa + 256);
  }
#undef ATT_STAGE
#undef ATT_COMPUTE

  float inv = (l_ > 1e-20f) ? (1.0f / l_) : 0.f;  // fully-masked row -> 0
  u16* obase = attnO + ((size_t)(b * 1024 + qb * 128 + w * 32)) * 1024 + h * 128;
#pragma unroll
  for (int r = 0; r < 16; ++r) {
    int qr = (r & 3) + 8 * (r >> 2) + 4 * hi;
    float iv = __shfl(inv, qr);
#pragma unroll
    for (int nb = 0; nb < 4; ++nb)
      obase[(size_t)qr * 1024 + nb * 32 + q32] = f2bf(oacc[nb][r] * iv);
  }
}

// ---------------------------------------------------------------------------
// fused residual + LayerNorm over 1024 cols. one block per row.
// ---------------------------------------------------------------------------
__global__ __launch_bounds__(256) void ln_fused(
    const float* __restrict__ aF, const u16* __restrict__ aBF,
    const u16* __restrict__ baddBF, const float* __restrict__ g,
    const float* __restrict__ bt, float* __restrict__ outF,
    u16* __restrict__ outBF) {
  const int row = blockIdx.x;
  const int c = threadIdx.x << 2;
  const size_t base = (size_t)row * 1024 + c;
  float4 h;
  if (aF) {
    h = *(const float4*)(aF + base);
  } else {
    u16x4 u = *(const u16x4*)(aBF + base);
    h.x = bf2f(u[0]); h.y = bf2f(u[1]); h.z = bf2f(u[2]); h.w = bf2f(u[3]);
  }
  if (baddBF) {
    u16x4 u = *(const u16x4*)(baddBF + base);
    h.x += bf2f(u[0]); h.y += bf2f(u[1]); h.z += bf2f(u[2]); h.w += bf2f(u[3]);
  }
  float s = (h.x + h.y) + (h.z + h.w);
  float q = (h.x * h.x + h.y * h.y) + (h.z * h.z + h.w * h.w);
#pragma unroll
  for (int msk = 1; msk < 64; msk <<= 1) {
    s += __shfl_xor(s, msk);
    q += __shfl_xor(q, msk);
  }
  __shared__ float sh[8];
  const int w = threadIdx.x >> 6;
  if ((threadIdx.x & 63) == 0) { sh[w] = s; sh[4 + w] = q; }
  __syncthreads();
  s = (sh[0] + sh[1]) + (sh[2] + sh[3]);
  q = (sh[4] + sh[5]) + (sh[6] + sh[7]);
  const float mu = s * (1.f / 1024.f);
  const float var = q * (1.f / 1024.f) - mu * mu;
  const float rstd = rsqrtf(var + 1e-5f);
  const float4 gv = *(const float4*)(g + c);
  const float4 bv = *(const float4*)(bt + c);
  float4 o;
  o.x = (h.x - mu) * rstd * gv.x + bv.x;
  o.y = (h.y - mu) * rstd * gv.y + bv.y;
  o.z = (h.z - mu) * rstd * gv.z + bv.z;
  o.w = (h.w - mu) * rstd * gv.w + bv.w;
  if (outF) *(float4*)(outF + base) = o;
  if (outBF) {
    u16x4 ub; ub[0] = f2bf(o.x); ub[1] = f2bf(o.y); ub[2] = f2bf(o.z); ub[3] = f2bf(o.w);
    *(u16x4*)(outBF + base) = ub;
  }
}

// ---------------------------------------------------------------------------
extern "C" void kernel_launch(void* const* d_in, const int* in_sizes, int n_in,
                              void* d_out, int out_size, void* d_ws, size_t ws_size,
                              hipStream_t stream) {
  const float* X  = (const float*)d_in[0];
  const float* Y  = (const float*)d_in[1];
  const void*  mask = d_in[2];
  const float* Wq = (const float*)d_in[3];
  const float* bq = (const float*)d_in[4];
  const float* Wk = (const float*)d_in[5];
  const float* bk = (const float*)d_in[6];
  const float* Wv = (const float*)d_in[7];
  const float* bv = (const float*)d_in[8];
  const float* Wo = (const float*)d_in[9];
  const float* bo = (const float*)d_in[10];
  const float* g1 = (const float*)d_in[11];
  const float* b1 = (const float*)d_in[12];
  const float* g2 = (const float*)d_in[13];
  const float* b2 = (const float*)d_in[14];
  float* out = (float*)d_out;

  char* ws = (char*)d_ws;
  const size_t MB = 1024ull * 1024ull;
  u16* Xbf    = (u16*)(ws + 0);         // 16MB, dead after Q-gemm -> O1bf
  u16* Ybf    = (u16*)(ws + 16 * MB);   // 16MB
  u16* Qbf    = (u16*)(ws + 32 * MB);   // 16MB (alive through LN1)
  u16* Kbf    = (u16*)(ws + 48 * MB);   // 16MB, dead after attn -> Rbf
  u16* Vt     = (u16*)(ws + 64 * MB);   // 16MB
  u16* attnbf = (u16*)(ws + 80 * MB);   // 16MB, dead after LN1
  u16* Wqt = (u16*)(ws + 112 * MB);
  u16* Wkt = (u16*)(ws + 114 * MB);
  u16* Wvt = (u16*)(ws + 116 * MB);
  u16* Wot = (u16*)(ws + 118 * MB);
  float* maskb = (float*)(ws + 120 * MB);  // 32KB
  u16* Rbf = Kbf;
  u16* O1bf = Xbf;

  prep_mask<<<dim3(32), dim3(256), 0, stream>>>((const u32*)mask, maskb);
  cvt_f2bf2<<<dim3(16384), dim3(256), 0, stream>>>(X, Xbf, Y, Ybf, 2097152);
  transpose_cvt<<<dim3(32, 32, 4), dim3(32, 8), 0, stream>>>(Wq, Wk, Wv, Wo, Wqt, Wkt, Wvt, Wot);

  gemm_nt<1><<<dim3(512), dim3(256), 0, stream>>>(Xbf, Wqt, bq, nullptr, Qbf, nullptr);
  gemm_nt<1><<<dim3(512), dim3(256), 0, stream>>>(Ybf, Wkt, bk, nullptr, Kbf, nullptr);
  gemm_nt<2><<<dim3(512), dim3(256), 0, stream>>>(Ybf, Wvt, bv, nullptr, Vt, nullptr);

  attn_fwd<<<dim3(512), dim3(256), 0, stream>>>(Qbf, Kbf, Vt, maskb, attnbf);

  ln_fused<<<dim3(8192), dim3(256), 0, stream>>>(nullptr, Qbf, attnbf, g1, b1, nullptr, O1bf);
  gemm_nt<3><<<dim3(512), dim3(256), 0, stream>>>(O1bf, Wot, bo, nullptr, Rbf, O1bf);
  ln_fused<<<dim3(8192), dim3(256), 0, stream>>>(nullptr, Rbf, nullptr, g2, b2, out, nullptr);
}